// Round 7
// baseline (87.403 us; speedup 1.0000x reference)
//
#include <hip/hip_runtime.h>

#define SEQ 1024
#define HEADS 16
#define HD 64
#define EMB 1024

typedef short bf16x8 __attribute__((ext_vector_type(8)));
typedef float f32x4 __attribute__((ext_vector_type(4)));

// float -> bf16 bits, round-to-nearest-even
static __device__ __forceinline__ unsigned short f2bf(float f) {
  unsigned u = __builtin_bit_cast(unsigned, f);
  u += 0x7FFFu + ((u >> 16) & 1u);
  return (unsigned short)(u >> 16);
}

// pack two f32 -> u32 of 2 bf16 (lo = a, hi = b)
static __device__ __forceinline__ unsigned cvtpk(float a, float b) {
  unsigned r;
  asm("v_cvt_pk_bf16_f32 %0, %1, %2" : "=v"(r) : "v"(a), "v"(b));
  return r;
}

static __device__ __forceinline__ void gload_lds16(const void* g, void* l) {
  __builtin_amdgcn_global_load_lds((const __attribute__((address_space(1))) unsigned int*)g,
                                   (__attribute__((address_space(3))) unsigned int*)l,
                                   16, 0, 0);
}

// ---------------- prep: mask bitpack + weight conversion (one launch) ----------------
// blocks [0,16384): mask [N,1,S,S] int32 -> mb[n][ktile][qrow] u64
// blocks [16384,17408): Wo f32 -> bf16 k-permuted wob
// block 17408: Wv/Wq/Wk -> bf16 row-major (Wq scaled by log2(e)/32)
__global__ __launch_bounds__(256) void k_prep(const int* __restrict__ mask,
                                              const float* __restrict__ Wo,
                                              const float* __restrict__ Wv,
                                              const float* __restrict__ Wq,
                                              const float* __restrict__ Wk,
                                              unsigned long long* __restrict__ mb,
                                              unsigned short* __restrict__ wob,
                                              unsigned short* __restrict__ wb) {
  const unsigned tid = threadIdx.x;
  if (blockIdx.x < 16384) {
    const unsigned gw = blockIdx.x * 4u + (tid >> 6);  // n*16384 + qrow*16 + ktile
    const unsigned lane = tid & 63u;
    const int v = mask[(size_t)gw * 64u + lane];
    const unsigned long long bits = __ballot(v != 0);
    if (lane == 0) {
      const unsigned n = gw >> 14, qrow = (gw >> 4) & 1023u, ktile = gw & 15u;
      mb[((size_t)n * 16 + ktile) * 1024 + qrow] = bits;
    }
  } else if (blockIdx.x < 17408) {
    const unsigned gid = (blockIdx.x - 16384) * 256u + tid;
    const unsigned e = gid >> 8, rem = gid & 255u;
    const unsigned blk = rem >> 4, cc = rem & 15u;
    const float* src = Wo + (size_t)e * 1024 + blk * 64 + cc;
    const unsigned w0 = cvtpk(src[0], src[16]);
    const unsigned w1 = cvtpk(src[32], src[48]);
    *(uint2*)(wob + (size_t)gid * 4) = make_uint2(w0, w1);
  } else {
    #pragma unroll
    for (int t = 0; t < 3; ++t) {
      const float* src = (t == 0) ? Wv : (t == 1) ? Wq : Wk;
      const float sc = (t == 1) ? 0.045084220027786356f : 1.0f;  // log2e/32 for Wq
      const float4 f0 = *(const float4*)(src + tid * 16);
      const float4 f1 = *(const float4*)(src + tid * 16 + 4);
      const float4 f2 = *(const float4*)(src + tid * 16 + 8);
      const float4 f3 = *(const float4*)(src + tid * 16 + 12);
      uint4 u0, u1;
      u0.x = cvtpk(f0.x * sc, f0.y * sc); u0.y = cvtpk(f0.z * sc, f0.w * sc);
      u0.z = cvtpk(f1.x * sc, f1.y * sc); u0.w = cvtpk(f1.z * sc, f1.w * sc);
      u1.x = cvtpk(f2.x * sc, f2.y * sc); u1.y = cvtpk(f2.z * sc, f2.w * sc);
      u1.z = cvtpk(f3.x * sc, f3.y * sc); u1.w = cvtpk(f3.z * sc, f3.w * sc);
      *(uint4*)(wb + t * 4096 + tid * 16) = u0;
      *(uint4*)(wb + t * 4096 + tid * 16 + 8) = u1;
    }
  }
}

// ---------------- projections ----------------
// Q/K -> [N][H][S][Dpi] bf16 (dpos = 4*(e&15)+(e>>4));  V -> V^T [N][H][D][S] bf16.
__global__ __launch_bounds__(256) void k_proj(const float* __restrict__ values,
                                              const float* __restrict__ query,
                                              const float* __restrict__ key,
                                              const unsigned short* __restrict__ wb,
                                              unsigned short* __restrict__ vb,
                                              unsigned short* __restrict__ qb,
                                              unsigned short* __restrict__ kb) {
  const int lane = threadIdx.x & 63;
  const int c = lane & 15, g = lane >> 4;
  const int wid = blockIdx.x * 4 + (threadIdx.x >> 6);
  const int t = wid >> 12;          // 0..2
  const int rem = wid & 4095;
  const int n = rem >> 10;
  const int h = (rem >> 6) & 15;
  const int lb = rem & 63;          // 16-row block index

  const float* x; unsigned short* out;
  if (t == 0)      { x = values; out = vb; }
  else if (t == 1) { x = query;  out = qb; }
  else             { x = key;    out = kb; }
  const unsigned short* W = wb + t * 4096;

  bf16x8 a[2];
  const float* xr = x + ((size_t)n * SEQ + lb * 16 + c) * EMB + h * HD;
  #pragma unroll
  for (int ks = 0; ks < 2; ++ks) {
    const float4 f0 = *(const float4*)(xr + ks * 32 + g * 8);
    const float4 f1 = *(const float4*)(xr + ks * 32 + g * 8 + 4);
    uint4 u;
    u.x = cvtpk(f0.x, f0.y); u.y = cvtpk(f0.z, f0.w);
    u.z = cvtpk(f1.x, f1.y); u.w = cvtpk(f1.z, f1.w);
    a[ks] = __builtin_bit_cast(bf16x8, u);
  }

  f32x4 acc[4] = {};
  #pragma unroll
  for (int cb = 0; cb < 4; ++cb) {
    #pragma unroll
    for (int ks = 0; ks < 2; ++ks) {
      const bf16x8 b = *(const bf16x8*)(W + (cb * 16 + c) * HD + ks * 32 + g * 8);
      acc[cb] = __builtin_amdgcn_mfma_f32_16x16x32_bf16(a[ks], b, acc[cb], 0, 0, 0);
    }
  }

  // acc[cb][r] = out[row = lb*16+4g+r][e = cb*16+c]
  if (t == 0) {
    unsigned short* vt = out + (size_t)(n * HEADS + h) * (HD * SEQ);
    const int key0 = lb * 16 + 4 * g;
    #pragma unroll
    for (int cb = 0; cb < 4; ++cb) {
      const unsigned w0 = cvtpk(acc[cb][0], acc[cb][1]);
      const unsigned w1 = cvtpk(acc[cb][2], acc[cb][3]);
      *(uint2*)(vt + (size_t)(cb * 16 + c) * SEQ + key0) = make_uint2(w0, w1);
    }
  } else {
    unsigned short* op = out + ((size_t)(n * HEADS + h) * SEQ + lb * 16) * HD;
    #pragma unroll
    for (int r = 0; r < 4; ++r) {
      const unsigned w0 = cvtpk(acc[0][r], acc[1][r]);
      const unsigned w1 = cvtpk(acc[2][r], acc[3][r]);
      *(uint2*)(op + (4 * g + r) * HD + 4 * c) = make_uint2(w0, w1);
    }
  }
}

// ---------------- flash attention, swapped QK^T, in-register P, counted-vmcnt pipeline ----
// block = (n, h, 64 q-rows); 4 waves x 16 q-rows. Grid 1024 (4/CU), bid%8 = nh%8 (XCD).
// S^T = mfma(A=K, B=Q); key permutation kappa folded into K staging source address.
// Loop: STAGE(t+1) -> vmcnt(4)+s_barrier -> compute(t) -> s_barrier  (prefetch stays in flight)
__global__ __launch_bounds__(256, 4) void k_attn(const unsigned short* __restrict__ qb,
                                                 const unsigned short* __restrict__ kb,
                                                 const unsigned short* __restrict__ vb,
                                                 const unsigned long long* __restrict__ mb,
                                                 unsigned short* __restrict__ ob) {
  const int tid = threadIdx.x;
  const int lane = tid & 63;
  const int c = lane & 15, g = lane >> 4;
  const int bid = blockIdx.x;
  const int nh = bid & 63, q64 = bid >> 6;
  const int n = nh >> 4, h = nh & 15;
  const int qlo = q64 * 64 + (tid >> 6) * 16;

  __shared__ unsigned short Ks[2][64][64];   // A-row rho holds key kappa(rho); col-swz ^(rho&7)
  __shared__ unsigned short Vs[2][64][64];   // V^T[d][keypos], col-swz ^(row&7)

  char* const Kb0 = (char*)&Ks[0][0][0];
  char* const Vb0 = (char*)&Vs[0][0][0];

  const size_t nhb = (size_t)(n * HEADS + h) * (SEQ * HD);
  const unsigned short* qp = qb + nhb;
  const char* kpB = (const char*)(kb + nhb);
  const char* vpB = (const char*)(vb + nhb);   // V^T [64][1024], row pitch 2048B

  // hoisted staging addresses (loop-invariant parts)
  const char* kSrc[2]; const char* vSrc[2]; int ldsOff[2];
  #pragma unroll
  for (int i = 0; i < 2; ++i) {
    const int off = i * 4096 + tid * 16;
    const int row = off >> 7, slot = (off >> 4) & 7;
    const int krow = ((row >> 4) & 1) * 32 + ((row >> 5) & 1) * 4 +
                     ((row >> 2) & 3) * 8 + (row & 3);
    const int sw = (slot ^ (row & 7)) << 4;
    kSrc[i] = kpB + krow * 128 + sw;
    vSrc[i] = vpB + (size_t)row * 2048 + sw;
    ldsOff[i] = off;
  }

  // Q B-frags: lane(c,g) = Q[qrow=qlo+c][dpos=ks*32+8g+j]
  bf16x8 qa[2];
  #pragma unroll
  for (int ks = 0; ks < 2; ++ks)
    qa[ks] = *(const bf16x8*)(qp + (size_t)(qlo + c) * HD + ks * 32 + g * 8);

  bf16x8 ones;
  #pragma unroll
  for (int j = 0; j < 8; ++j) ones[j] = (short)0x3F80;

  f32x4 o[4] = {};
  f32x4 lacc = {};

#define STAGEKV(dstK, dstV, kt_) do {                                   \
    _Pragma("unroll")                                                   \
    for (int i = 0; i < 2; ++i) {                                       \
      gload_lds16(kSrc[i] + (size_t)(kt_) * 8192, (dstK) + ldsOff[i]);  \
      gload_lds16(vSrc[i] + (kt_) * 128, (dstV) + ldsOff[i]);           \
    }                                                                   \
  } while (0)

  STAGEKV(Kb0, Vb0, 0);

  for (int kt = 0; kt < 16; ++kt) {
    const int cur = kt & 1;
    char* const Kc = Kb0 + cur * 8192;
    char* const Vc = Vb0 + cur * 8192;
    if (kt < 15) {
      STAGEKV(Kb0 + (cur ^ 1) * 8192, Vb0 + (cur ^ 1) * 8192, kt + 1);
      asm volatile("s_waitcnt vmcnt(4)" ::: "memory");   // tile kt done, kt+1 in flight
    } else {
      asm volatile("s_waitcnt vmcnt(0)" ::: "memory");
    }
    asm volatile("s_barrier" ::: "memory");

    // mask row for this lane's qrow (=qlo+c)
    const unsigned long long bits = mb[((size_t)(n * 16 + kt)) * 1024 + qlo + c];
    const unsigned blo = (unsigned)bits, bhi = (unsigned)(bits >> 32);

    // K A-frags: kf[sub][ks] lane(c,g) = A[row=c] of subtile sub = K[kappa(sub,c)]
    bf16x8 kf[4][2];
    #pragma unroll
    for (int sub = 0; sub < 4; ++sub) {
      const int rho = sub * 16 + c;     // rho&7 == c&7
      #pragma unroll
      for (int ks = 0; ks < 2; ++ks)
        kf[sub][ks] = *(const bf16x8*)(Kc + rho * 128 + (((ks * 4 + g) ^ (c & 7)) << 4));
    }

    // S^T = K * Q^T : s[sub] lane(c,g) = S[key=kappa(sub,4g+r)][qrow=c]
    f32x4 s[4];
    __builtin_amdgcn_s_setprio(1);
    #pragma unroll
    for (int sub = 0; sub < 4; ++sub) {
      f32x4 acc = {};
      acc = __builtin_amdgcn_mfma_f32_16x16x32_bf16(kf[sub][0], qa[0], acc, 0, 0, 0);
      acc = __builtin_amdgcn_mfma_f32_16x16x32_bf16(kf[sub][1], qa[1], acc, 0, 0, 0);
      s[sub] = acc;
    }
    __builtin_amdgcn_s_setprio(0);

    // V^T B-frags issued before the exp2 block (LDS latency hides under VALU)
    bf16x8 vf[4][2];
    #pragma unroll
    for (int db = 0; db < 4; ++db) {
      const int row = db * 16 + c;
      #pragma unroll
      for (int ks = 0; ks < 2; ++ks)
        vf[db][ks] = *(const bf16x8*)(Vc + row * 128 + (((ks * 4 + g) ^ (c & 7)) << 4));
    }

    // softmax numerators, in-register, directly into PV A-frag word order
    unsigned pw[2][4];
    #pragma unroll
    for (int sub = 0; sub < 4; ++sub) {
      const unsigned x = ((sub & 1) ? bhi : blo) >> (8 * g + ((sub >> 1) << 2));
      const float p0 = (x & 1u) ? __builtin_exp2f(s[sub][0]) : 0.f;
      const float p1 = (x & 2u) ? __builtin_exp2f(s[sub][1]) : 0.f;
      const float p2 = (x & 4u) ? __builtin_exp2f(s[sub][2]) : 0.f;
      const float p3 = (x & 8u) ? __builtin_exp2f(s[sub][3]) : 0.f;
      pw[sub & 1][(sub >> 1) * 2 + 0] = cvtpk(p0, p1);
      pw[sub & 1][(sub >> 1) * 2 + 1] = cvtpk(p2, p3);
    }
    bf16x8 pa[2];
    pa[0] = __builtin_bit_cast(bf16x8, *(uint4*)&pw[0][0]);
    pa[1] = __builtin_bit_cast(bf16x8, *(uint4*)&pw[1][0]);

    // O += P V ; l += P * ones
    __builtin_amdgcn_s_setprio(1);
    #pragma unroll
    for (int ks = 0; ks < 2; ++ks) {
      #pragma unroll
      for (int db = 0; db < 4; ++db)
        o[db] = __builtin_amdgcn_mfma_f32_16x16x32_bf16(pa[ks], vf[db][ks], o[db], 0, 0, 0);
      lacc = __builtin_amdgcn_mfma_f32_16x16x32_bf16(pa[ks], ones, lacc, 0, 0, 0);
    }
    __builtin_amdgcn_s_setprio(0);

    if (kt < 15) asm volatile("s_barrier" ::: "memory");   // readers done before next overwrite
  }
#undef STAGEKV

  // epilogue: lane(c,g) holds O[qrow=4g+r][e=db*16+c], l[qrow=4g+r]
  #pragma unroll
  for (int r = 0; r < 4; ++r) {
    const float inv = 1.0f / lacc[r];
    const unsigned w0 = cvtpk(o[0][r] * inv, o[1][r] * inv);
    const unsigned w1 = cvtpk(o[2][r] * inv, o[3][r] * inv);
    *(uint2*)(ob + ((size_t)n * SEQ + qlo + 4 * g + r) * EMB + h * 64 + 4 * c) =
        make_uint2(w0, w1);
  }
}

// ---------------- out-proj GEMM: C[4096,1024] = A[4096,1024pi] * B[1024,1024pi]^T + bo ----------------
// 64x64 tile, BK=64, grid 1024 (4/CU), swizzled dbuf LDS, counted-vmcnt pipeline.
__global__ __launch_bounds__(256, 4) void k_gemm(const unsigned short* __restrict__ A,
                                                 const unsigned short* __restrict__ B,
                                                 const float* __restrict__ bo,
                                                 float* __restrict__ C) {
  const int tid = threadIdx.x;
  const int w = tid >> 6, lane = tid & 63;
  const int c = lane & 15, g = lane >> 4;
  const int bm = blockIdx.x & 63, bn = blockIdx.x >> 6;
  const int m0 = bm * 64, n0 = bn * 64;
  const int wr = w >> 1, wc = w & 1;

  __shared__ unsigned short As[2][64][64];
  __shared__ unsigned short Bs[2][64][64];

  // hoisted staging addresses
  const char* aSrc[2]; const char* bSrc[2]; int ldsOff[2];
  #pragma unroll
  for (int i = 0; i < 2; ++i) {
    const int off = i * 4096 + tid * 16;
    const int row = off >> 7, slot = (off >> 4) & 7;
    const int sw = (slot ^ (row & 7)) << 4;
    aSrc[i] = (const char*)A + (size_t)(m0 + row) * 2048 + sw;
    bSrc[i] = (const char*)B + (size_t)(n0 + row) * 2048 + sw;
    ldsOff[i] = off;
  }

  f32x4 acc[2][2] = {};

#define STAGE(buf, kt_) do {                                                  \
    _Pragma("unroll")                                                         \
    for (int i = 0; i < 2; ++i) {                                             \
      gload_lds16(aSrc[i] + (kt_) * 128, (char*)&As[buf][0][0] + ldsOff[i]);  \
      gload_lds16(bSrc[i] + (kt_) * 128, (char*)&Bs[buf][0][0] + ldsOff[i]);  \
    }                                                                         \
  } while (0)

  STAGE(0, 0);

  for (int kt = 0; kt < 16; ++kt) {
    const int cur = kt & 1;
    if (kt < 15) {
      STAGE(cur ^ 1, kt + 1);
      asm volatile("s_waitcnt vmcnt(4)" ::: "memory");
    } else {
      asm volatile("s_waitcnt vmcnt(0)" ::: "memory");
    }
    asm volatile("s_barrier" ::: "memory");

    #pragma unroll
    for (int ks = 0; ks < 2; ++ks) {
      bf16x8 af[2], bf_[2];
      #pragma unroll
      for (int i = 0; i < 2; ++i) {
        const int row = wr * 32 + i * 16 + c;   // row&7 == c&7
        af[i] = *(const bf16x8*)((char*)&As[cur][0][0] + row * 128 +
                                 (((ks * 4 + g) ^ (c & 7)) << 4));
      }
      #pragma unroll
      for (int j = 0; j < 2; ++j) {
        const int row = wc * 32 + j * 16 + c;
        bf_[j] = *(const bf16x8*)((char*)&Bs[cur][0][0] + row * 128 +
                                  (((ks * 4 + g) ^ (c & 7)) << 4));
      }
      __builtin_amdgcn_s_setprio(1);
      #pragma unroll
      for (int i = 0; i < 2; ++i)
        #pragma unroll
        for (int j = 0; j < 2; ++j)
          acc[i][j] = __builtin_amdgcn_mfma_f32_16x16x32_bf16(af[i], bf_[j], acc[i][j], 0, 0, 0);
      __builtin_amdgcn_s_setprio(0);
    }

    if (kt < 15) asm volatile("s_barrier" ::: "memory");
  }
#undef STAGE

  #pragma unroll
  for (int j = 0; j < 2; ++j) {
    const int col = n0 + wc * 32 + j * 16 + c;
    const float bv = bo[col];
    #pragma unroll
    for (int i = 0; i < 2; ++i) {
      const int rowb = m0 + wr * 32 + i * 16 + 4 * g;
      #pragma unroll
      for (int r = 0; r < 4; ++r)
        C[(size_t)(rowb + r) * 1024 + col] = acc[i][j][r] + bv;
    }
  }
}

extern "C" void kernel_launch(void* const* d_in, const int* in_sizes, int n_in,
                              void* d_out, int out_size, void* d_ws, size_t ws_size,
                              hipStream_t stream) {
  const float* values = (const float*)d_in[0];
  const float* query  = (const float*)d_in[1];
  const float* key    = (const float*)d_in[2];
  const int*   mask   = (const int*)d_in[3];
  const float* Wv     = (const float*)d_in[4];
  const float* Wk     = (const float*)d_in[5];
  const float* Wq     = (const float*)d_in[6];
  const float* Wo     = (const float*)d_in[7];
  const float* bo     = (const float*)d_in[8];
  float* out = (float*)d_out;

  char* ws = (char*)d_ws;
  unsigned short* qb = (unsigned short*)(ws);                            // 8MB  [N][H][S][Dpi]
  unsigned short* kb = (unsigned short*)(ws + (size_t)8 * 1024 * 1024);  // 8MB  [N][H][S][Dpi]
  unsigned short* vb = (unsigned short*)(ws + (size_t)16 * 1024 * 1024); // 8MB  V^T [N][H][D][S]
  unsigned short* ob = (unsigned short*)(ws + (size_t)24 * 1024 * 1024); // 8MB  [N][S][Epi]
  unsigned long long* mb = (unsigned long long*)(ws + (size_t)32 * 1024 * 1024);   // 512KB
  unsigned short* wb  = (unsigned short*)(ws + (size_t)32 * 1024 * 1024 + 512 * 1024); // 24KB
  unsigned short* wob = (unsigned short*)(ws + (size_t)33 * 1024 * 1024);          // 2MB

  k_prep<<<17409, 256, 0, stream>>>(mask, Wo, Wv, Wq, Wk, mb, wob, wb);
  k_proj<<<3072, 256, 0, stream>>>(values, query, key, wb, vb, qb, kb);
  k_attn<<<1024, 256, 0, stream>>>(qb, kb, vb, mb, ob);
  k_gemm<<<1024, 256, 0, stream>>>(ob, wob, bo, out);
}

// Round 8
// 76.771 us; speedup vs baseline: 1.1385x; 1.1385x over previous
//
#include <hip/hip_runtime.h>

#define SEQ 1024
#define HEADS 16
#define HD 64
#define EMB 1024

typedef short bf16x8 __attribute__((ext_vector_type(8)));
typedef float f32x4 __attribute__((ext_vector_type(4)));

// pack two f32 -> u32 of 2 bf16 (lo = a, hi = b)
static __device__ __forceinline__ unsigned cvtpk(float a, float b) {
  unsigned r;
  asm("v_cvt_pk_bf16_f32 %0, %1, %2" : "=v"(r) : "v"(a), "v"(b));
  return r;
}

static __device__ __forceinline__ void gload_lds16(const void* g, void* l) {
  __builtin_amdgcn_global_load_lds((const __attribute__((address_space(1))) unsigned int*)g,
                                   (__attribute__((address_space(3))) unsigned int*)l,
                                   16, 0, 0);
}

// ---------------- fused prep + projections ----------------
// blocks [0,3072): projections (W converted to LDS per block)
//   Q/K -> [N][H][S][Dpi] bf16 (dpos = 4*(e&15)+(e>>4));  V -> V^T [N][H][D][S] bf16.
// blocks [3072,7168): mask [N,1,S,S] int32 -> mb[n][ktile][qrow] u64 (4 gw per wave)
// blocks [7168,8192): Wo f32 -> bf16 k-permuted wob
__global__ __launch_bounds__(256) void k_pp(const int* __restrict__ mask,
                                            const float* __restrict__ Wo,
                                            const float* __restrict__ Wv,
                                            const float* __restrict__ Wq,
                                            const float* __restrict__ Wk,
                                            const float* __restrict__ values,
                                            const float* __restrict__ query,
                                            const float* __restrict__ key,
                                            unsigned long long* __restrict__ mb,
                                            unsigned short* __restrict__ wob,
                                            unsigned short* __restrict__ vb,
                                            unsigned short* __restrict__ qb,
                                            unsigned short* __restrict__ kb) {
  __shared__ unsigned short Wl[64][64];
  const unsigned tid = threadIdx.x;
  const unsigned b = blockIdx.x;

  if (b < 3072) {
    const int lane = tid & 63, c = lane & 15, g = lane >> 4;
    const int wid = b * 4 + (tid >> 6);
    const int t = wid >> 12;          // 0..2 (uniform per block)
    const int rem = wid & 4095;
    const int n = rem >> 10, h = (rem >> 6) & 15, lb = rem & 63;

    const float* x; unsigned short* out;
    if (t == 0)      { x = values; out = vb; }
    else if (t == 1) { x = query;  out = qb; }
    else             { x = key;    out = kb; }
    const float* Wf = (t == 0) ? Wv : (t == 1) ? Wq : Wk;
    const float sc = (t == 1) ? 0.045084220027786356f : 1.0f;  // log2e/32 for Wq

    // stage W f32 -> bf16 into swizzled LDS
    {
      const int row = tid >> 2, c0 = (tid & 3) * 16;
      const float4 f0 = *(const float4*)(Wf + row * 64 + c0);
      const float4 f1 = *(const float4*)(Wf + row * 64 + c0 + 4);
      const float4 f2 = *(const float4*)(Wf + row * 64 + c0 + 8);
      const float4 f3 = *(const float4*)(Wf + row * 64 + c0 + 12);
      uint4 u0, u1;
      u0.x = cvtpk(f0.x * sc, f0.y * sc); u0.y = cvtpk(f0.z * sc, f0.w * sc);
      u0.z = cvtpk(f1.x * sc, f1.y * sc); u0.w = cvtpk(f1.z * sc, f1.w * sc);
      u1.x = cvtpk(f2.x * sc, f2.y * sc); u1.y = cvtpk(f2.z * sc, f2.w * sc);
      u1.z = cvtpk(f3.x * sc, f3.y * sc); u1.w = cvtpk(f3.z * sc, f3.w * sc);
      const int s0 = ((c0 >> 3) ^ (row & 7)) << 4;
      const int s1 = (((c0 >> 3) + 1) ^ (row & 7)) << 4;
      *(uint4*)((char*)&Wl[0][0] + row * 128 + s0) = u0;
      *(uint4*)((char*)&Wl[0][0] + row * 128 + s1) = u1;
    }
    __syncthreads();

    // B-frags from LDS: bfr[cb][ks] lane(c,g) = W[e=cb*16+c][d=ks*32+8g+j]
    bf16x8 bfr[4][2];
    #pragma unroll
    for (int cb = 0; cb < 4; ++cb) {
      const int row = cb * 16 + c;
      #pragma unroll
      for (int ks = 0; ks < 2; ++ks)
        bfr[cb][ks] = *(const bf16x8*)((char*)&Wl[0][0] + row * 128 +
                                       (((ks * 4 + g) ^ (c & 7)) << 4));
    }

    bf16x8 a[2];
    const float* xr = x + ((size_t)n * SEQ + lb * 16 + c) * EMB + h * HD;
    #pragma unroll
    for (int ks = 0; ks < 2; ++ks) {
      const float4 f0 = *(const float4*)(xr + ks * 32 + g * 8);
      const float4 f1 = *(const float4*)(xr + ks * 32 + g * 8 + 4);
      uint4 u;
      u.x = cvtpk(f0.x, f0.y); u.y = cvtpk(f0.z, f0.w);
      u.z = cvtpk(f1.x, f1.y); u.w = cvtpk(f1.z, f1.w);
      a[ks] = __builtin_bit_cast(bf16x8, u);
    }

    f32x4 acc[4] = {};
    #pragma unroll
    for (int cb = 0; cb < 4; ++cb)
      #pragma unroll
      for (int ks = 0; ks < 2; ++ks)
        acc[cb] = __builtin_amdgcn_mfma_f32_16x16x32_bf16(a[ks], bfr[cb][ks], acc[cb], 0, 0, 0);

    // acc[cb][r] = out[row = lb*16+4g+r][e = cb*16+c]
    if (t == 0) {
      unsigned short* vt = out + (size_t)(n * HEADS + h) * (HD * SEQ);
      const int key0 = lb * 16 + 4 * g;
      #pragma unroll
      for (int cb = 0; cb < 4; ++cb) {
        const unsigned w0 = cvtpk(acc[cb][0], acc[cb][1]);
        const unsigned w1 = cvtpk(acc[cb][2], acc[cb][3]);
        *(uint2*)(vt + (size_t)(cb * 16 + c) * SEQ + key0) = make_uint2(w0, w1);
      }
    } else {
      unsigned short* op = out + ((size_t)(n * HEADS + h) * SEQ + lb * 16) * HD;
      #pragma unroll
      for (int r = 0; r < 4; ++r) {
        const unsigned w0 = cvtpk(acc[0][r], acc[1][r]);
        const unsigned w1 = cvtpk(acc[2][r], acc[3][r]);
        *(uint2*)(op + (4 * g + r) * HD + 4 * c) = make_uint2(w0, w1);
      }
    }
  } else if (b < 7168) {
    const unsigned lane = tid & 63u;
    const unsigned gwb = (b - 3072) * 16u + (tid >> 6) * 4u;
    #pragma unroll
    for (int it = 0; it < 4; ++it) {
      const unsigned gw = gwb + it;   // n*16384 + qrow*16 + ktile
      const int v = mask[(size_t)gw * 64u + lane];
      const unsigned long long bits = __ballot(v != 0);
      if (lane == 0) {
        const unsigned n = gw >> 14, qrow = (gw >> 4) & 1023u, ktile = gw & 15u;
        mb[((size_t)n * 16 + ktile) * 1024 + qrow] = bits;
      }
    }
  } else {
    const unsigned gid = (b - 7168) * 256u + tid;
    const unsigned e = gid >> 8, rem = gid & 255u;
    const unsigned blk = rem >> 4, cc = rem & 15u;
    const float* src = Wo + (size_t)e * 1024 + blk * 64 + cc;
    const unsigned w0 = cvtpk(src[0], src[16]);
    const unsigned w1 = cvtpk(src[32], src[48]);
    *(uint2*)(wob + (size_t)gid * 4) = make_uint2(w0, w1);
  }
}

// ---------------- flash attention: swapped QK^T, in-register P, 32 q-rows/wave ----------
// block = (n, h, 128 q-rows); 4 waves x 32 q-rows (2 groups of 16). Grid 512 (2/CU).
// KVBLK=128: 2 k-tiles per barrier period, double-buffered (64 KB LDS), vmcnt(8) counted.
// S^T = mfma(A=K, B=Q); kappa key permutation folded into K staging source address.
__global__ __launch_bounds__(256, 2) void k_attn(const unsigned short* __restrict__ qb,
                                                 const unsigned short* __restrict__ kb,
                                                 const unsigned short* __restrict__ vb,
                                                 const unsigned long long* __restrict__ mb,
                                                 unsigned short* __restrict__ ob) {
  const int tid = threadIdx.x;
  const int w = tid >> 6, lane = tid & 63;
  const int c = lane & 15, g = lane >> 4;
  const int bid = blockIdx.x;
  const int nh = bid & 63, q128 = bid >> 6;
  const int n = nh >> 4, h = nh & 15;
  const int qlo = q128 * 128 + w * 32;

  __shared__ unsigned short Ks[2][2][64][64];  // [buf][tile][A-row rho][64], col-swz ^(rho&7)
  __shared__ unsigned short Vs[2][2][64][64];  // [buf][tile][d][keypos], col-swz ^(d&7)

  char* const Kb0 = (char*)&Ks[0][0][0][0];
  char* const Vb0 = (char*)&Vs[0][0][0][0];

  const size_t nhb = (size_t)(n * HEADS + h) * (SEQ * HD);
  const unsigned short* qp = qb + nhb;
  const char* kpB = (const char*)(kb + nhb);
  const char* vpB = (const char*)(vb + nhb);   // V^T [64][1024], row pitch 2048B

  // hoisted staging addresses: 4 K + 4 V loads per thread per 2-tile period
  const char* kSrc[4]; const char* vSrc[4]; int ldsOff[4];
  #pragma unroll
  for (int i = 0; i < 4; ++i) {
    const int off = i * 4096 + tid * 16;        // 0..16383
    const int row = off >> 7;                   // 0..127
    const int tile = row >> 6, r64 = row & 63;
    const int slot = (off >> 4) & 7;
    const int krow = ((r64 >> 4) & 1) * 32 + ((r64 >> 5) & 1) * 4 +
                     ((r64 >> 2) & 3) * 8 + (r64 & 3);   // kappa
    const int sw = (slot ^ (r64 & 7)) << 4;
    kSrc[i] = kpB + (size_t)(tile * 64 + krow) * 128 + sw;
    vSrc[i] = vpB + (size_t)r64 * 2048 + tile * 128 + sw;  // r64 = d for V
    ldsOff[i] = off;
  }

  // Q B-frags: qa[grp][ks] lane(c,g) = Q[qlo+grp*16+c][dpos=ks*32+8g+j]
  bf16x8 qa[2][2];
  #pragma unroll
  for (int grp = 0; grp < 2; ++grp)
    #pragma unroll
    for (int ks = 0; ks < 2; ++ks)
      qa[grp][ks] = *(const bf16x8*)(qp + (size_t)(qlo + grp * 16 + c) * HD + ks * 32 + g * 8);

  bf16x8 ones;
  #pragma unroll
  for (int j = 0; j < 8; ++j) ones[j] = (short)0x3F80;

  f32x4 o[2][4] = {};
  f32x4 lacc[2] = {};

#define STAGEKV(dstK, dstV, kp_) do {                                    \
    _Pragma("unroll")                                                    \
    for (int i = 0; i < 4; ++i) {                                        \
      gload_lds16(kSrc[i] + (size_t)(kp_) * 16384, (dstK) + ldsOff[i]);  \
      gload_lds16(vSrc[i] + (kp_) * 256, (dstV) + ldsOff[i]);            \
    }                                                                    \
  } while (0)

  STAGEKV(Kb0, Vb0, 0);

  for (int kp = 0; kp < 8; ++kp) {
    const int cur = kp & 1;
    if (kp < 7) {
      STAGEKV(Kb0 + (cur ^ 1) * 16384, Vb0 + (cur ^ 1) * 16384, kp + 1);
      asm volatile("s_waitcnt vmcnt(8)" ::: "memory");  // period kp done, kp+1 in flight
    } else {
      asm volatile("s_waitcnt vmcnt(0)" ::: "memory");
    }
    asm volatile("s_barrier" ::: "memory");

    #pragma unroll
    for (int t = 0; t < 2; ++t) {
      const int kt = kp * 2 + t;
      char* const Kc = Kb0 + cur * 16384 + t * 8192;
      char* const Vc = Vb0 + cur * 16384 + t * 8192;

      // mask rows for both groups (qrow = qlo + grp*16 + c), issue early
      const unsigned long long bits0 = mb[((size_t)(n * 16 + kt)) * 1024 + qlo + c];
      const unsigned long long bits1 = mb[((size_t)(n * 16 + kt)) * 1024 + qlo + 16 + c];

      // K A-frags (shared by both groups): kf[sub][ks] = K[kappa(sub,c)]
      bf16x8 kf[4][2];
      #pragma unroll
      for (int sub = 0; sub < 4; ++sub) {
        const int rho = sub * 16 + c;     // rho&7 == c&7
        #pragma unroll
        for (int ks = 0; ks < 2; ++ks)
          kf[sub][ks] = *(const bf16x8*)(Kc + rho * 128 + (((ks * 4 + g) ^ (c & 7)) << 4));
      }
      // V^T B-frags (shared): vf[db][ks] = V^T[d=db*16+c][key=ks*32+8g+j]
      bf16x8 vf[4][2];
      #pragma unroll
      for (int db = 0; db < 4; ++db) {
        const int row = db * 16 + c;
        #pragma unroll
        for (int ks = 0; ks < 2; ++ks)
          vf[db][ks] = *(const bf16x8*)(Vc + row * 128 + (((ks * 4 + g) ^ (c & 7)) << 4));
      }

      #pragma unroll
      for (int grp = 0; grp < 2; ++grp) {
        const unsigned long long bits = grp ? bits1 : bits0;
        const unsigned blo = (unsigned)bits, bhi = (unsigned)(bits >> 32);

        f32x4 s[4];
        __builtin_amdgcn_s_setprio(1);
        #pragma unroll
        for (int sub = 0; sub < 4; ++sub) {
          f32x4 acc = {};
          acc = __builtin_amdgcn_mfma_f32_16x16x32_bf16(kf[sub][0], qa[grp][0], acc, 0, 0, 0);
          acc = __builtin_amdgcn_mfma_f32_16x16x32_bf16(kf[sub][1], qa[grp][1], acc, 0, 0, 0);
          s[sub] = acc;
        }
        __builtin_amdgcn_s_setprio(0);

        // softmax numerators -> PV A-frag word order, in-register
        unsigned pw[2][4];
        #pragma unroll
        for (int sub = 0; sub < 4; ++sub) {
          const unsigned x = ((sub & 1) ? bhi : blo) >> (8 * g + ((sub >> 1) << 2));
          const float p0 = (x & 1u) ? __builtin_exp2f(s[sub][0]) : 0.f;
          const float p1 = (x & 2u) ? __builtin_exp2f(s[sub][1]) : 0.f;
          const float p2 = (x & 4u) ? __builtin_exp2f(s[sub][2]) : 0.f;
          const float p3 = (x & 8u) ? __builtin_exp2f(s[sub][3]) : 0.f;
          pw[sub & 1][(sub >> 1) * 2 + 0] = cvtpk(p0, p1);
          pw[sub & 1][(sub >> 1) * 2 + 1] = cvtpk(p2, p3);
        }
        bf16x8 pa[2];
        pa[0] = __builtin_bit_cast(bf16x8, *(uint4*)&pw[0][0]);
        pa[1] = __builtin_bit_cast(bf16x8, *(uint4*)&pw[1][0]);

        __builtin_amdgcn_s_setprio(1);
        #pragma unroll
        for (int ks = 0; ks < 2; ++ks) {
          #pragma unroll
          for (int db = 0; db < 4; ++db)
            o[grp][db] = __builtin_amdgcn_mfma_f32_16x16x32_bf16(pa[ks], vf[db][ks], o[grp][db], 0, 0, 0);
          lacc[grp] = __builtin_amdgcn_mfma_f32_16x16x32_bf16(pa[ks], ones, lacc[grp], 0, 0, 0);
        }
        __builtin_amdgcn_s_setprio(0);
      }
    }

    if (kp < 7) asm volatile("s_barrier" ::: "memory");   // readers done before overwrite
  }
#undef STAGEKV

  // epilogue: lane(c,g) holds O[qrow=qlo+grp*16+4g+r][e=db*16+c], l same rows
  #pragma unroll
  for (int grp = 0; grp < 2; ++grp)
    #pragma unroll
    for (int r = 0; r < 4; ++r) {
      const float inv = 1.0f / lacc[grp][r];
      const unsigned w0 = cvtpk(o[grp][0][r] * inv, o[grp][1][r] * inv);
      const unsigned w1 = cvtpk(o[grp][2][r] * inv, o[grp][3][r] * inv);
      *(uint2*)(ob + ((size_t)n * SEQ + qlo + grp * 16 + 4 * g + r) * EMB + h * 64 + 4 * c) =
          make_uint2(w0, w1);
    }
}

// ---------------- out-proj GEMM: C[4096,1024] = A[4096,1024pi] * B[1024,1024pi]^T + bo ----------------
// 128x64 tile, BK=64, grid 512 (2/CU), swizzled dbuf LDS, counted-vmcnt pipeline.
__global__ __launch_bounds__(256, 2) void k_gemm(const unsigned short* __restrict__ A,
                                                 const unsigned short* __restrict__ B,
                                                 const float* __restrict__ bo,
                                                 float* __restrict__ C) {
  const int tid = threadIdx.x;
  const int w = tid >> 6, lane = tid & 63;
  const int c = lane & 15, g = lane >> 4;
  const int bm = blockIdx.x & 31, bn = blockIdx.x >> 5;
  const int m0 = bm * 128, n0 = bn * 64;

  __shared__ unsigned short As[2][128][64];
  __shared__ unsigned short Bs[2][64][64];

  // hoisted staging addresses: 4 A + 2 B loads per thread per K-step
  const char* aSrc[4]; int aOff[4];
  const char* bSrc[2]; int bOff[2];
  #pragma unroll
  for (int i = 0; i < 4; ++i) {
    const int off = i * 4096 + tid * 16;
    const int row = off >> 7, slot = (off >> 4) & 7;
    const int sw = (slot ^ (row & 7)) << 4;
    aSrc[i] = (const char*)A + (size_t)(m0 + row) * 2048 + sw;
    aOff[i] = off;
  }
  #pragma unroll
  for (int i = 0; i < 2; ++i) {
    const int off = i * 4096 + tid * 16;
    const int row = off >> 7, slot = (off >> 4) & 7;
    const int sw = (slot ^ (row & 7)) << 4;
    bSrc[i] = (const char*)B + (size_t)(n0 + row) * 2048 + sw;
    bOff[i] = off;
  }

  f32x4 acc[2][4] = {};

#define STAGE(buf, kt_) do {                                                  \
    _Pragma("unroll")                                                         \
    for (int i = 0; i < 4; ++i)                                               \
      gload_lds16(aSrc[i] + (kt_) * 128, (char*)&As[buf][0][0] + aOff[i]);    \
    _Pragma("unroll")                                                         \
    for (int i = 0; i < 2; ++i)                                               \
      gload_lds16(bSrc[i] + (kt_) * 128, (char*)&Bs[buf][0][0] + bOff[i]);    \
  } while (0)

  STAGE(0, 0);

  for (int kt = 0; kt < 16; ++kt) {
    const int cur = kt & 1;
    if (kt < 15) {
      STAGE(cur ^ 1, kt + 1);
      asm volatile("s_waitcnt vmcnt(6)" ::: "memory");
    } else {
      asm volatile("s_waitcnt vmcnt(0)" ::: "memory");
    }
    asm volatile("s_barrier" ::: "memory");

    #pragma unroll
    for (int ks = 0; ks < 2; ++ks) {
      bf16x8 af[2], bf_[4];
      #pragma unroll
      for (int i = 0; i < 2; ++i) {
        const int row = w * 32 + i * 16 + c;   // row&7 == c&7
        af[i] = *(const bf16x8*)((char*)&As[cur][0][0] + row * 128 +
                                 (((ks * 4 + g) ^ (c & 7)) << 4));
      }
      #pragma unroll
      for (int j = 0; j < 4; ++j) {
        const int row = j * 16 + c;
        bf_[j] = *(const bf16x8*)((char*)&Bs[cur][0][0] + row * 128 +
                                  (((ks * 4 + g) ^ (c & 7)) << 4));
      }
      __builtin_amdgcn_s_setprio(1);
      #pragma unroll
      for (int i = 0; i < 2; ++i)
        #pragma unroll
        for (int j = 0; j < 4; ++j)
          acc[i][j] = __builtin_amdgcn_mfma_f32_16x16x32_bf16(af[i], bf_[j], acc[i][j], 0, 0, 0);
      __builtin_amdgcn_s_setprio(0);
    }

    if (kt < 15) asm volatile("s_barrier" ::: "memory");
  }
#undef STAGE

  #pragma unroll
  for (int j = 0; j < 4; ++j) {
    const int col = n0 + j * 16 + c;
    const float bv = bo[col];
    #pragma unroll
    for (int i = 0; i < 2; ++i) {
      const int rowb = m0 + w * 32 + i * 16 + 4 * g;
      #pragma unroll
      for (int r = 0; r < 4; ++r)
        C[(size_t)(rowb + r) * 1024 + col] = acc[i][j][r] + bv;
    }
  }
}

extern "C" void kernel_launch(void* const* d_in, const int* in_sizes, int n_in,
                              void* d_out, int out_size, void* d_ws, size_t ws_size,
                              hipStream_t stream) {
  const float* values = (const float*)d_in[0];
  const float* query  = (const float*)d_in[1];
  const float* key    = (const float*)d_in[2];
  const int*   mask   = (const int*)d_in[3];
  const float* Wv     = (const float*)d_in[4];
  const float* Wk     = (const float*)d_in[5];
  const float* Wq     = (const float*)d_in[6];
  const float* Wo     = (const float*)d_in[7];
  const float* bo     = (const float*)d_in[8];
  float* out = (float*)d_out;

  char* ws = (char*)d_ws;
  unsigned short* qb = (unsigned short*)(ws);                            // 8MB  [N][H][S][Dpi]
  unsigned short* kb = (unsigned short*)(ws + (size_t)8 * 1024 * 1024);  // 8MB  [N][H][S][Dpi]
  unsigned short* vb = (unsigned short*)(ws + (size_t)16 * 1024 * 1024); // 8MB  V^T [N][H][D][S]
  unsigned short* ob = (unsigned short*)(ws + (size_t)24 * 1024 * 1024); // 8MB  [N][S][Epi]
  unsigned long long* mb = (unsigned long long*)(ws + (size_t)32 * 1024 * 1024);   // 512KB
  unsigned short* wob = (unsigned short*)(ws + (size_t)33 * 1024 * 1024);          // 2MB

  k_pp<<<8192, 256, 0, stream>>>(mask, Wo, Wv, Wq, Wk, values, query, key, mb, wob, vb, qb, kb);
  k_attn<<<512, 256, 0, stream>>>(qb, kb, vb, mb, ob);
  k_gemm<<<512, 256, 0, stream>>>(ob, wob, bo, out);
}